// Round 5
// baseline (473.765 us; speedup 1.0000x reference)
//
#include <hip/hip_runtime.h>
#include <hip/hip_bf16.h>

typedef unsigned short u16;
typedef __bf16 bf16x8 __attribute__((ext_vector_type(8)));
typedef float f32x4 __attribute__((ext_vector_type(4)));

#define AS1 __attribute__((address_space(1)))
#define AS3 __attribute__((address_space(3)))

__device__ inline u16 f2bf(float f) {
  union { float f; unsigned int u; } c; c.f = f;
  unsigned int u = c.u;
  return (u16)((u + 0x7fffu + ((u >> 16) & 1u)) >> 16);
}

// ---------------- fp32 -> bf16 conversion ----------------
__global__ __launch_bounds__(256) void cvt_f32_bf16(const float* __restrict__ in,
                                                    u16* __restrict__ out, int n4) {
  int i = blockIdx.x * 256 + threadIdx.x;
  if (i >= n4) return;
  float4 v = reinterpret_cast<const float4*>(in)[i];
  ushort4 o;
  o.x = f2bf(v.x); o.y = f2bf(v.y); o.z = f2bf(v.z); o.w = f2bf(v.w);
  reinterpret_cast<ushort4*>(out)[i] = o;
}

// ============ 256x256 NT GEMM, BK=64, 8 waves, 4-phase, balanced ds_reads ======
// C[m,n] = scale * sum_k A[m,k]*B[n,k].  M,N mult of 256; K mult of 128 (NT even,
// NT>=4). LDS: 2 x (A[256][64]+B[256][64]) bf16 = 128 KiB, XOR-swizzled
// (byte^=(row&7)<<4), pre-swizzled global source. Stage slots per tile t:
// ph0->B0(t+1), ph1->A1(t+1), ph2->A0(t+2), ph3->B1(t+2). Single vmcnt per tile
// at ph3: vmcnt(4 events = 2 half-tiles) retires everything except
// {A0(t+2),B1(t+2)} => tile t+1 fully resident; ph3 then pre-reads next tile's
// A-lo frags (8/8/0/8 ds_read balance; max 8 per phase).

__device__ __forceinline__ void stage_half(const u16* __restrict__ g, long ld, int k0,
                                           u16* dst, int t) {
#pragma unroll
  for (int i = 0; i < 2; ++i) {
    const int c = i * 512 + t;
    const int r = c >> 3;
    const int s = c & 7;
    const int col = ((s ^ (r & 7)) << 3) + k0;   // pre-swizzled global source
    __builtin_amdgcn_global_load_lds((const AS1 void*)(g + (long)r * ld + col),
                                     (AS3 void*)(dst + c * 8), 16, 0, 0);
  }
}

__device__ __forceinline__ bf16x8 frag_ld(const u16* s, int row, int colb) {
  return *reinterpret_cast<const bf16x8*>(
      reinterpret_cast<const char*>(s) + row * 128 + (colb ^ ((row & 7) << 4)));
}

#define BAR_PRE()       do { asm volatile("" ::: "memory"); \
                             __builtin_amdgcn_s_barrier(); \
                             asm volatile("" ::: "memory"); } while (0)
#define BAR_PRE_VM()    do { asm volatile("s_waitcnt vmcnt(4)" ::: "memory"); \
                             __builtin_amdgcn_s_barrier(); \
                             asm volatile("" ::: "memory"); } while (0)
#define BAR_POST()      do { asm volatile("" ::: "memory"); \
                             __builtin_amdgcn_s_barrier(); \
                             asm volatile("" ::: "memory"); } while (0)

__device__ __forceinline__ void tile_body(
    const u16* __restrict__ Ab, long lda, const u16* __restrict__ Bb, long ldb,
    u16* bc, u16* bn, int k1, int k2, int t,
    int wm, int wn, int lhi, int llo,
    bf16x8 (&aLo)[4][2], bf16x8 (&aNx)[4][2], f32x4 (&acc)[2][4][2][2])
{
  const u16* sBc = bc + 16384;
  bf16x8 aHi[4][2], bl[2][2], bh[2][2];

  // ---- ph0: stage B0(t+1); read bl(4) + aHi kk0(4); MFMA (Alo,Blo)
  stage_half(Bb, ldb, k1, bn + 16384, t);
#pragma unroll
  for (int fc = 0; fc < 2; ++fc)
#pragma unroll
    for (int kk = 0; kk < 2; ++kk)
      bl[fc][kk] = frag_ld(sBc, wn * 32 + fc * 16 + llo, (kk << 6) + (lhi << 4));
#pragma unroll
  for (int fr = 0; fr < 4; ++fr)
    aHi[fr][0] = frag_ld(bc, 128 + wm * 64 + fr * 16 + llo, (lhi << 4));
  BAR_PRE();
  __builtin_amdgcn_s_setprio(1);
#pragma unroll
  for (int fr = 0; fr < 4; ++fr)
#pragma unroll
    for (int fc = 0; fc < 2; ++fc)
#pragma unroll
      for (int kk = 0; kk < 2; ++kk)
        acc[0][fr][0][fc] = __builtin_amdgcn_mfma_f32_16x16x32_bf16(aLo[fr][kk], bl[fc][kk], acc[0][fr][0][fc], 0, 0, 0);
  __builtin_amdgcn_s_setprio(0);
  BAR_POST();

  // ---- ph1: stage A1(t+1); read bh(4) + aHi kk1(4); MFMA (Alo,Bhi)
  stage_half(Ab + 128 * lda, lda, k1, bn + 8192, t);
#pragma unroll
  for (int fc = 0; fc < 2; ++fc)
#pragma unroll
    for (int kk = 0; kk < 2; ++kk)
      bh[fc][kk] = frag_ld(sBc, 128 + wn * 32 + fc * 16 + llo, (kk << 6) + (lhi << 4));
#pragma unroll
  for (int fr = 0; fr < 4; ++fr)
    aHi[fr][1] = frag_ld(bc, 128 + wm * 64 + fr * 16 + llo, (1 << 6) + (lhi << 4));
  BAR_PRE();
  __builtin_amdgcn_s_setprio(1);
#pragma unroll
  for (int fr = 0; fr < 4; ++fr)
#pragma unroll
    for (int fc = 0; fc < 2; ++fc)
#pragma unroll
      for (int kk = 0; kk < 2; ++kk)
        acc[0][fr][1][fc] = __builtin_amdgcn_mfma_f32_16x16x32_bf16(aLo[fr][kk], bh[fc][kk], acc[0][fr][1][fc], 0, 0, 0);
  __builtin_amdgcn_s_setprio(0);
  BAR_POST();

  // ---- ph2: stage A0(t+2); no reads; MFMA (Ahi,Bhi)
  stage_half(Ab, lda, k2, bc, t);
  BAR_PRE();
  __builtin_amdgcn_s_setprio(1);
#pragma unroll
  for (int fr = 0; fr < 4; ++fr)
#pragma unroll
    for (int fc = 0; fc < 2; ++fc)
#pragma unroll
      for (int kk = 0; kk < 2; ++kk)
        acc[1][fr][1][fc] = __builtin_amdgcn_mfma_f32_16x16x32_bf16(aHi[fr][kk], bh[fc][kk], acc[1][fr][1][fc], 0, 0, 0);
  __builtin_amdgcn_s_setprio(0);
  BAR_POST();

  // ---- ph3: stage B1(t+2); vmcnt(4) => tile t+1 resident; pre-read next A-lo(8);
  //      MFMA (Ahi,Blo)
  stage_half(Bb + 128 * ldb, ldb, k2, bc + 16384 + 8192, t);
  BAR_PRE_VM();
#pragma unroll
  for (int fr = 0; fr < 4; ++fr)
#pragma unroll
    for (int kk = 0; kk < 2; ++kk)
      aNx[fr][kk] = frag_ld(bn, wm * 64 + fr * 16 + llo, (kk << 6) + (lhi << 4));
  __builtin_amdgcn_s_setprio(1);
#pragma unroll
  for (int fr = 0; fr < 4; ++fr)
#pragma unroll
    for (int fc = 0; fc < 2; ++fc)
#pragma unroll
      for (int kk = 0; kk < 2; ++kk)
        acc[1][fr][0][fc] = __builtin_amdgcn_mfma_f32_16x16x32_bf16(aHi[fr][kk], bl[fc][kk], acc[1][fr][0][fc], 0, 0, 0);
  __builtin_amdgcn_s_setprio(0);
  BAR_POST();
}

template<bool OUT_F32>
__global__ __launch_bounds__(512, 2) void gemm_nt256(
    const u16* __restrict__ A, long lda, long sAz4, long sAz1,
    const u16* __restrict__ B, long ldb, long sBz4, long sBz1,
    void* __restrict__ Cv, long ldc, long sCz4, long sCz1,
    long cBatch, int cShift,
    int K, float scale)
{
  __shared__ u16 sm[2 * 32768] __attribute__((aligned(16)));  // 128 KiB

  const int t = threadIdx.x;
  // T1: bijective XCD-chunked block swizzle (nwg % 8 == 0 for all our grids)
  int wg = blockIdx.x + gridDim.x * blockIdx.y;
  const int nwg = gridDim.x * gridDim.y;
  const int qq = nwg >> 3;
  wg = (wg & 7) * qq + (wg >> 3);
  const long m0 = (long)(wg % gridDim.x) * 256;
  const long n0 = (long)(wg / gridDim.x) * 256;
  const int z = blockIdx.z;
  const long azoff = (long)(z >> 2) * sAz4 + (long)(z & 3) * sAz1;
  const long bzoff = (long)(z >> 2) * sBz4 + (long)(z & 3) * sBz1;
  const u16* Ab = A + azoff + m0 * lda;
  const u16* Bb = B + bzoff + n0 * ldb;

  const int wid = t >> 6, lane = t & 63;
  const int lhi = lane >> 4, llo = lane & 15;
  const int wm = wid >> 2, wn = wid & 3;  // wave rows {wm*64,128+wm*64}, cols {wn*32,128+wn*32}

  f32x4 acc[2][4][2][2] = {};
  bf16x8 aA[4][2], aB[4][2];

  const int NT = K >> 6;   // even, >= 4

  // prologue, age order: tile0's 4 halves first, then A0(1), B1(1)
  stage_half(Ab, lda, 0, sm, t);
  stage_half(Bb + 128 * ldb, ldb, 0, sm + 16384 + 8192, t);
  stage_half(Bb, ldb, 0, sm + 16384, t);
  stage_half(Ab + 128 * lda, lda, 0, sm + 8192, t);
  stage_half(Ab, lda, 64, sm + 32768, t);
  stage_half(Bb + 128 * ldb, ldb, 64, sm + 32768 + 16384 + 8192, t);
  asm volatile("s_waitcnt vmcnt(4)" ::: "memory");  // tile0 resident; A0(1),B1(1) in flight
  __builtin_amdgcn_s_barrier();
  asm volatile("" ::: "memory");
  // read tile0's A-lo frags
#pragma unroll
  for (int fr = 0; fr < 4; ++fr)
#pragma unroll
    for (int kk = 0; kk < 2; ++kk)
      aA[fr][kk] = frag_ld(sm, wm * 64 + fr * 16 + llo, (kk << 6) + (lhi << 4));

  for (int i = 0; i < NT; i += 2) {
    const int k1a = ((i + 1 < NT) ? i + 1 : 0) << 6;
    const int k2a = ((i + 2 < NT) ? i + 2 : i + 2 - NT) << 6;
    const int k2b = ((i + 3 < NT) ? i + 3 : i + 3 - NT) << 6;
    tile_body(Ab, lda, Bb, ldb, sm, sm + 32768, k1a, k2a, t, wm, wn, lhi, llo, aA, aB, acc);
    tile_body(Ab, lda, Bb, ldb, sm + 32768, sm, k2a, k2b, t, wm, wn, lhi, llo, aB, aA, acc);
  }

  // epilogue: C/D frag row=(lane>>4)*4+e, col=lane&15; column fold for batch-major C
  const long cb = n0 >> cShift;
  const long ncol0 = n0 - (cb << cShift);
  const long czoff = (long)(z >> 2) * sCz4 + (long)(z & 3) * sCz1 + cb * cBatch;
#pragma unroll
  for (int ah = 0; ah < 2; ++ah)
#pragma unroll
    for (int fr = 0; fr < 4; ++fr)
#pragma unroll
      for (int e = 0; e < 4; ++e) {
        const long r = m0 + ah * 128 + wm * 64 + fr * 16 + lhi * 4 + e;
#pragma unroll
        for (int bh2 = 0; bh2 < 2; ++bh2)
#pragma unroll
          for (int fc = 0; fc < 2; ++fc) {
            const long col = ncol0 + bh2 * 128 + wn * 32 + fc * 16 + llo;
            const float val = acc[ah][fr][bh2][fc][e] * scale;
            if (OUT_F32)
              ((float*)Cv)[czoff + r * ldc + col] = val;
            else
              ((u16*)Cv)[czoff + r * ldc + col] = f2bf(val);
          }
      }
}

// ---- softmax over rows of att = sum of 4 split-K partials [16][1024][1024] f32 ----
__global__ __launch_bounds__(256) void softmax_reduce4(const float* __restrict__ att,
                                                       u16* __restrict__ P) {
  const long row = blockIdx.x;            // b*1024 + r
  const long b = row >> 10;
  const int t = threadIdx.x;
  float4 v; v.x = 0.f; v.y = 0.f; v.z = 0.f; v.w = 0.f;
#pragma unroll
  for (int p = 0; p < 4; ++p) {
    const float4 u = reinterpret_cast<const float4*>(att)[((b * 4 + p) << 18) + ((row & 1023) << 8) + t];
    v.x += u.x; v.y += u.y; v.z += u.z; v.w += u.w;
  }
  float m = fmaxf(fmaxf(v.x, v.y), fmaxf(v.z, v.w));
#pragma unroll
  for (int off = 32; off > 0; off >>= 1) m = fmaxf(m, __shfl_down(m, off, 64));
  __shared__ float smax[4], ssum[4];
  const int wid = t >> 6, lane = t & 63;
  if (lane == 0) smax[wid] = m;
  __syncthreads();
  m = fmaxf(fmaxf(smax[0], smax[1]), fmaxf(smax[2], smax[3]));
  float e0 = expf(v.x - m), e1 = expf(v.y - m), e2 = expf(v.z - m), e3 = expf(v.w - m);
  float s = e0 + e1 + e2 + e3;
#pragma unroll
  for (int off = 32; off > 0; off >>= 1) s += __shfl_down(s, off, 64);
  if (lane == 0) ssum[wid] = s;
  __syncthreads();
  s = ssum[0] + ssum[1] + ssum[2] + ssum[3];
  float inv = 1.0f / s;
  ushort4 o;
  o.x = f2bf(e0 * inv); o.y = f2bf(e1 * inv); o.z = f2bf(e2 * inv); o.w = f2bf(e3 * inv);
  reinterpret_cast<ushort4*>(P + row * 1024)[t] = o;
}

extern "C" void kernel_launch(void* const* d_in, const int* in_sizes, int n_in,
                              void* d_out, int out_size, void* d_ws, size_t ws_size,
                              hipStream_t stream) {
  const float* x  = (const float*)d_in[0];
  const float* Wq = (const float*)d_in[1];
  const float* Wk = (const float*)d_in[2];
  const float* Wv = (const float*)d_in[3];
  const float* Wo = (const float*)d_in[4];

  const long Bz = 4, L = 4096, E = 1024;
  const long BL = Bz * L;                 // 16384 tokens

  // workspace layout (u16 elements)
  u16* xbf  = (u16*)d_ws;                 // [16384][1024]
  u16* wqk  = xbf + BL * E;               // [2048][1024]  (Wq rows 0-1023, Wk 1024-2047)
  u16* wv   = wqk + 2048L * 1024;         // [1024][1024]
  u16* wo   = wv + 1024L * 1024;          // [1024][1024]
  u16* qhat = wo + 1024L * 1024;          // [4][1024][4096] batch-major qT
  u16* khat = qhat + 4L * 1024 * 4096;    // [4][1024][4096] batch-major kT
  u16* vbuf = khat + 4L * 1024 * 4096;    // [16384][1024]
  // aliases (disjoint lifetimes):
  u16* P    = qhat;                       // [4][1024][1024] bf16 (qhat dead after stage 2)
  u16* outb = xbf;                        // [16384][1024] bf16 (xbf dead after stage 1b)
  float* attp = (float*)d_out;            // [16][1024][1024] f32 split-K partials (64 MB)

  dim3 b256(256), b512(512);
  const long NOF = 0;                     // no fold
  const int NSH = 30;

  // conversions
  cvt_f32_bf16<<<dim3((BL * E / 4 + 255) / 256), b256, 0, stream>>>(x, xbf, (int)(BL * E / 4));
  cvt_f32_bf16<<<dim3(1024), b256, 0, stream>>>(Wq, wqk, 1024 * 1024 / 4);
  cvt_f32_bf16<<<dim3(1024), b256, 0, stream>>>(Wk, wqk + 1024L * 1024, 1024 * 1024 / 4);
  cvt_f32_bf16<<<dim3(1024), b256, 0, stream>>>(Wv, wv, 1024 * 1024 / 4);
  cvt_f32_bf16<<<dim3(1024), b256, 0, stream>>>(Wo, wo, 1024 * 1024 / 4);

  // stage 1a (merged q+k): z=0 -> qhat = Wq @ xbf^T, z=1 -> khat = Wk @ xbf^T
  // (M=1024, N=16384 folded by 4096, K=1024)
  gemm_nt256<false><<<dim3(4, 64, 2), b512, 0, stream>>>(
      wqk, 1024, 0, 1024L * 1024, xbf, 1024, 0, 0,
      (void*)qhat, 4096, 0, 4L * 1024 * 4096, 1024L * 4096, 12, 1024, 1.0f);
  // stage 1b: v = xbf @ Wv^T  (M=16384, N=1024, K=1024)
  gemm_nt256<false><<<dim3(64, 4, 1), b512, 0, stream>>>(
      xbf, 1024, 0, 0, wv, 1024, 0, 0,
      (void*)vbuf, 1024, 0, 0, NOF, NSH, 1024, 1.0f);
  // stage 2: att partials; z=b*4+p: A/B offset = b*(1024*4096) + p*1024 (lda=4096)
  gemm_nt256<true><<<dim3(4, 4, 16), b512, 0, stream>>>(
      qhat, 4096, 1L << 22, 1024, khat, 4096, 1L << 22, 1024,
      (void*)attp, 1024, 4L << 20, 1L << 20, NOF, NSH, 1024, 1.0f / 32.0f);
  // stage 3: reduce partials + softmax -> P bf16
  softmax_reduce4<<<dim3(4096), b256, 0, stream>>>(attp, P);
  // stage 4: out[b] = v[b] @ P[b]^T  (M=4096, N=1024, K=1024, z=b)
  gemm_nt256<false><<<dim3(16, 4, 4), b512, 0, stream>>>(
      vbuf, 1024, 0, 1L << 22, P, 1024, 0, 1L << 20,
      (void*)outb, 1024, 0, 1L << 22, NOF, NSH, 1024, 1.0f);
  // stage 5: final = out @ Wo^T  (M=16384, N=1024, K=1024) -> d_out fp32
  gemm_nt256<true><<<dim3(64, 4, 1), b512, 0, stream>>>(
      outb, 1024, 0, 0, wo, 1024, 0, 0,
      d_out, 1024, 0, 0, NOF, NSH, 1024, 1.0f);
}

// Round 6
// 280.875 us; speedup vs baseline: 1.6868x; 1.6868x over previous
//
#include <hip/hip_runtime.h>
#include <hip/hip_bf16.h>

typedef unsigned short u16;
typedef __bf16 bf16x8 __attribute__((ext_vector_type(8)));
typedef float f32x4 __attribute__((ext_vector_type(4)));

#define AS1 __attribute__((address_space(1)))
#define AS3 __attribute__((address_space(3)))

__device__ inline u16 f2bf(float f) {
  union { float f; unsigned int u; } c; c.f = f;
  unsigned int u = c.u;
  return (u16)((u + 0x7fffu + ((u >> 16) & 1u)) >> 16);
}

// ---------------- fp32 -> bf16 conversion ----------------
__global__ __launch_bounds__(256) void cvt_f32_bf16(const float* __restrict__ in,
                                                    u16* __restrict__ out, int n4) {
  int i = blockIdx.x * 256 + threadIdx.x;
  if (i >= n4) return;
  float4 v = reinterpret_cast<const float4*>(in)[i];
  ushort4 o;
  o.x = f2bf(v.x); o.y = f2bf(v.y); o.z = f2bf(v.z); o.w = f2bf(v.w);
  reinterpret_cast<ushort4*>(out)[i] = o;
}

// ============ 256x256 NT GEMM, BK=64, 8 waves, 4-phase, vmcnt(6)/phase ========
// C[m,n] = scale * sum_k A[m,k]*B[n,k].  M,N mult of 256; K mult of 64, K/64>=4.
// LDS: 2 x (A[256][64]+B[256][64]) bf16 = 128 KiB, XOR-swizzled (byte^=(row&7)<<4)
// with pre-swizzled global source. Stage slots: ph0->B0(t+1), ph1->A1(t+1),
// ph2->A0(t+2), ph3->B1(t+2). UNIFORM vmcnt(6) before every phase barrier (the
// R3-proven pacing: each phase retires exactly one half-tile, spreading the
// drain; each half-tile retires >=1 barrier before its first ds_read).
// z-offset = (z>>2)*sZ4 + (z&3)*sZ1 (split-K column chunks). C column fold:
// batch = n0>>cShift (tiles never span folds).

__device__ __forceinline__ void stage_half(const u16* __restrict__ g, long ld, int k0,
                                           u16* dst, int t) {
#pragma unroll
  for (int i = 0; i < 2; ++i) {
    const int c = i * 512 + t;
    const int r = c >> 3;
    const int s = c & 7;
    const int col = ((s ^ (r & 7)) << 3) + k0;   // pre-swizzled global source
    __builtin_amdgcn_global_load_lds((const AS1 void*)(g + (long)r * ld + col),
                                     (AS3 void*)(dst + c * 8), 16, 0, 0);
  }
}

__device__ __forceinline__ bf16x8 frag_ld(const u16* s, int row, int colb) {
  return *reinterpret_cast<const bf16x8*>(
      reinterpret_cast<const char*>(s) + row * 128 + (colb ^ ((row & 7) << 4)));
}

#define BAR_PRE()       do { asm volatile("s_waitcnt vmcnt(6)" ::: "memory"); \
                             __builtin_amdgcn_s_barrier(); \
                             asm volatile("" ::: "memory"); } while (0)
#define BAR_POST()      do { asm volatile("" ::: "memory"); \
                             __builtin_amdgcn_s_barrier(); \
                             asm volatile("" ::: "memory"); } while (0)

template<bool OUT_F32>
__global__ __launch_bounds__(512, 2) void gemm_nt256(
    const u16* __restrict__ A, long lda, long sAz4, long sAz1,
    const u16* __restrict__ B, long ldb, long sBz4, long sBz1,
    void* __restrict__ Cv, long ldc, long sCz4, long sCz1,
    long cBatch, int cShift,
    int K, float scale)
{
  __shared__ u16 sm[2 * 32768] __attribute__((aligned(16)));  // 128 KiB

  const int t = threadIdx.x;
  // T1: bijective XCD-chunked block swizzle (nwg % 8 == 0 for all our grids)
  int wg = blockIdx.x + gridDim.x * blockIdx.y;
  const int nwg = gridDim.x * gridDim.y;
  const int qq = nwg >> 3;
  wg = (wg & 7) * qq + (wg >> 3);
  const long m0 = (long)(wg % gridDim.x) * 256;
  const long n0 = (long)(wg / gridDim.x) * 256;
  const int z = blockIdx.z;
  const long azoff = (long)(z >> 2) * sAz4 + (long)(z & 3) * sAz1;
  const long bzoff = (long)(z >> 2) * sBz4 + (long)(z & 3) * sBz1;
  const u16* Ab = A + azoff + m0 * lda;
  const u16* Bb = B + bzoff + n0 * ldb;

  const int wid = t >> 6, lane = t & 63;
  const int lhi = lane >> 4, llo = lane & 15;
  const int wm = wid >> 2, wn = wid & 3;  // wave rows {wm*64, 128+wm*64}, cols {wn*32, 128+wn*32}

  f32x4 acc[2][4][2][2] = {};

  const int NT = K >> 6;

  // prologue, age order: A0(0), B1(0), B0(0), A1(0), A0(1), B1(1)
  stage_half(Ab, lda, 0, sm, t);
  stage_half(Bb + 128 * ldb, ldb, 0, sm + 16384 + 8192, t);
  stage_half(Bb, ldb, 0, sm + 16384, t);
  stage_half(Ab + 128 * lda, lda, 0, sm + 8192, t);
  stage_half(Ab, lda, 64, sm + 32768, t);
  stage_half(Bb + 128 * ldb, ldb, 64, sm + 32768 + 16384 + 8192, t);
  asm volatile("s_waitcnt vmcnt(4)" ::: "memory");  // tile0 done; A0(1),B1(1) in flight
  __builtin_amdgcn_s_barrier();
  asm volatile("" ::: "memory");

  for (int kt = 0; kt < NT; ++kt) {
    const int kb = kt & 1;
    u16* bc = sm + kb * 32768;          // current tile buffer
    u16* bn = sm + (kb ^ 1) * 32768;    // next tile buffer
    const u16* sAc = bc;
    const u16* sBc = bc + 16384;
    const int k1 = ((kt + 1 < NT) ? kt + 1 : 0) << 6;            // wrapped (dead) at tail
    const int k2 = ((kt + 2 < NT) ? kt + 2 : kt + 2 - NT) << 6;

    bf16x8 a[4][2], bl[2][2], bh[2][2];

    // ---- ph0: stage B0(t+1) -> bn; read A-lo(8) + B-lo(4); MFMA (Alo,Blo)
    stage_half(Bb, ldb, k1, bn + 16384, t);
#pragma unroll
    for (int fr = 0; fr < 4; ++fr)
#pragma unroll
      for (int kk = 0; kk < 2; ++kk)
        a[fr][kk] = frag_ld(sAc, wm * 64 + fr * 16 + llo, (kk << 6) + (lhi << 4));
#pragma unroll
    for (int fc = 0; fc < 2; ++fc)
#pragma unroll
      for (int kk = 0; kk < 2; ++kk)
        bl[fc][kk] = frag_ld(sBc, wn * 32 + fc * 16 + llo, (kk << 6) + (lhi << 4));
    BAR_PRE();
    __builtin_amdgcn_s_setprio(1);
#pragma unroll
    for (int fr = 0; fr < 4; ++fr)
#pragma unroll
      for (int fc = 0; fc < 2; ++fc)
#pragma unroll
        for (int kk = 0; kk < 2; ++kk)
          acc[0][fr][0][fc] = __builtin_amdgcn_mfma_f32_16x16x32_bf16(a[fr][kk], bl[fc][kk], acc[0][fr][0][fc], 0, 0, 0);
    __builtin_amdgcn_s_setprio(0);
    BAR_POST();

    // ---- ph1: stage A1(t+1) -> bn; read B-hi(4); MFMA (Alo,Bhi)
    stage_half(Ab + 128 * lda, lda, k1, bn + 8192, t);
#pragma unroll
    for (int fc = 0; fc < 2; ++fc)
#pragma unroll
      for (int kk = 0; kk < 2; ++kk)
        bh[fc][kk] = frag_ld(sBc, 128 + wn * 32 + fc * 16 + llo, (kk << 6) + (lhi << 4));
    BAR_PRE();
    __builtin_amdgcn_s_setprio(1);
#pragma unroll
    for (int fr = 0; fr < 4; ++fr)
#pragma unroll
      for (int fc = 0; fc < 2; ++fc)
#pragma unroll
        for (int kk = 0; kk < 2; ++kk)
          acc[0][fr][1][fc] = __builtin_amdgcn_mfma_f32_16x16x32_bf16(a[fr][kk], bh[fc][kk], acc[0][fr][1][fc], 0, 0, 0);
    __builtin_amdgcn_s_setprio(0);
    BAR_POST();

    // ---- ph2: stage A0(t+2) -> bc A-lo (dead); read A-hi(8); MFMA (Ahi,Bhi)
    stage_half(Ab, lda, k2, bc, t);
#pragma unroll
    for (int fr = 0; fr < 4; ++fr)
#pragma unroll
      for (int kk = 0; kk < 2; ++kk)
        a[fr][kk] = frag_ld(sAc, 128 + wm * 64 + fr * 16 + llo, (kk << 6) + (lhi << 4));
    BAR_PRE();
    __builtin_amdgcn_s_setprio(1);
#pragma unroll
    for (int fr = 0; fr < 4; ++fr)
#pragma unroll
      for (int fc = 0; fc < 2; ++fc)
#pragma unroll
        for (int kk = 0; kk < 2; ++kk)
          acc[1][fr][1][fc] = __builtin_amdgcn_mfma_f32_16x16x32_bf16(a[fr][kk], bh[fc][kk], acc[1][fr][1][fc], 0, 0, 0);
    __builtin_amdgcn_s_setprio(0);
    BAR_POST();

    // ---- ph3: stage B1(t+2) -> bc B-hi (dead); MFMA (Ahi,Blo)
    stage_half(Bb + 128 * ldb, ldb, k2, bc + 16384 + 8192, t);
    BAR_PRE();
    __builtin_amdgcn_s_setprio(1);
#pragma unroll
    for (int fr = 0; fr < 4; ++fr)
#pragma unroll
      for (int fc = 0; fc < 2; ++fc)
#pragma unroll
        for (int kk = 0; kk < 2; ++kk)
          acc[1][fr][0][fc] = __builtin_amdgcn_mfma_f32_16x16x32_bf16(a[fr][kk], bl[fc][kk], acc[1][fr][0][fc], 0, 0, 0);
    __builtin_amdgcn_s_setprio(0);
    BAR_POST();
  }

  // epilogue: C/D frag row=(lane>>4)*4+e, col=lane&15; column fold for batch-major C
  const long cb = n0 >> cShift;
  const long ncol0 = n0 - (cb << cShift);
  const long czoff = (long)(z >> 2) * sCz4 + (long)(z & 3) * sCz1 + cb * cBatch;
#pragma unroll
  for (int ah = 0; ah < 2; ++ah)
#pragma unroll
    for (int fr = 0; fr < 4; ++fr)
#pragma unroll
      for (int e = 0; e < 4; ++e) {
        const long r = m0 + ah * 128 + wm * 64 + fr * 16 + lhi * 4 + e;
#pragma unroll
        for (int bh2 = 0; bh2 < 2; ++bh2)
#pragma unroll
          for (int fc = 0; fc < 2; ++fc) {
            const long col = ncol0 + bh2 * 128 + wn * 32 + fc * 16 + llo;
            const float val = acc[ah][fr][bh2][fc][e] * scale;
            if (OUT_F32)
              ((float*)Cv)[czoff + r * ldc + col] = val;
            else
              ((u16*)Cv)[czoff + r * ldc + col] = f2bf(val);
          }
      }
}

// ---- softmax over rows of att = sum of 4 split-K partials [16][1024][1024] f32 ----
__global__ __launch_bounds__(256) void softmax_reduce4(const float* __restrict__ att,
                                                       u16* __restrict__ P) {
  const long row = blockIdx.x;            // b*1024 + r
  const long b = row >> 10;
  const int t = threadIdx.x;
  float4 v; v.x = 0.f; v.y = 0.f; v.z = 0.f; v.w = 0.f;
#pragma unroll
  for (int p = 0; p < 4; ++p) {
    const float4 u = reinterpret_cast<const float4*>(att)[((b * 4 + p) << 18) + ((row & 1023) << 8) + t];
    v.x += u.x; v.y += u.y; v.z += u.z; v.w += u.w;
  }
  float m = fmaxf(fmaxf(v.x, v.y), fmaxf(v.z, v.w));
#pragma unroll
  for (int off = 32; off > 0; off >>= 1) m = fmaxf(m, __shfl_down(m, off, 64));
  __shared__ float smax[4], ssum[4];
  const int wid = t >> 6, lane = t & 63;
  if (lane == 0) smax[wid] = m;
  __syncthreads();
  m = fmaxf(fmaxf(smax[0], smax[1]), fmaxf(smax[2], smax[3]));
  float e0 = expf(v.x - m), e1 = expf(v.y - m), e2 = expf(v.z - m), e3 = expf(v.w - m);
  float s = e0 + e1 + e2 + e3;
#pragma unroll
  for (int off = 32; off > 0; off >>= 1) s += __shfl_down(s, off, 64);
  if (lane == 0) ssum[wid] = s;
  __syncthreads();
  s = ssum[0] + ssum[1] + ssum[2] + ssum[3];
  float inv = 1.0f / s;
  ushort4 o;
  o.x = f2bf(e0 * inv); o.y = f2bf(e1 * inv); o.z = f2bf(e2 * inv); o.w = f2bf(e3 * inv);
  reinterpret_cast<ushort4*>(P + row * 1024)[t] = o;
}

extern "C" void kernel_launch(void* const* d_in, const int* in_sizes, int n_in,
                              void* d_out, int out_size, void* d_ws, size_t ws_size,
                              hipStream_t stream) {
  const float* x  = (const float*)d_in[0];
  const float* Wq = (const float*)d_in[1];
  const float* Wk = (const float*)d_in[2];
  const float* Wv = (const float*)d_in[3];
  const float* Wo = (const float*)d_in[4];

  const long Bz = 4, L = 4096, E = 1024;
  const long BL = Bz * L;                 // 16384 tokens

  // workspace layout (u16 elements)
  u16* xbf  = (u16*)d_ws;                 // [16384][1024]
  u16* wqk  = xbf + BL * E;               // [2048][1024]  (Wq rows 0-1023, Wk 1024-2047)
  u16* wv   = wqk + 2048L * 1024;         // [1024][1024]
  u16* wo   = wv + 1024L * 1024;          // [1024][1024]
  u16* qhat = wo + 1024L * 1024;          // [4][1024][4096] batch-major qT
  u16* khat = qhat + 4L * 1024 * 4096;    // [4][1024][4096] batch-major kT
  u16* vbuf = khat + 4L * 1024 * 4096;    // [16384][1024]
  // aliases (disjoint lifetimes):
  u16* P    = qhat;                       // [4][1024][1024] bf16 (qhat dead after stage 2)
  u16* outb = xbf;                        // [16384][1024] bf16 (xbf dead after stage 1b)
  float* attp = (float*)d_out;            // [16][1024][1024] f32 split-K partials (64 MB)

  dim3 b256(256), b512(512);
  const long NOF = 0;                     // no fold
  const int NSH = 30;

  // conversions
  cvt_f32_bf16<<<dim3((BL * E / 4 + 255) / 256), b256, 0, stream>>>(x, xbf, (int)(BL * E / 4));
  cvt_f32_bf16<<<dim3(1024), b256, 0, stream>>>(Wq, wqk, 1024 * 1024 / 4);
  cvt_f32_bf16<<<dim3(1024), b256, 0, stream>>>(Wk, wqk + 1024L * 1024, 1024 * 1024 / 4);
  cvt_f32_bf16<<<dim3(1024), b256, 0, stream>>>(Wv, wv, 1024 * 1024 / 4);
  cvt_f32_bf16<<<dim3(1024), b256, 0, stream>>>(Wo, wo, 1024 * 1024 / 4);

  // stage 1a (merged q+k): z=0 -> qhat = Wq @ xbf^T, z=1 -> khat = Wk @ xbf^T
  // (M=1024, N=16384 folded by 4096, K=1024)
  gemm_nt256<false><<<dim3(4, 64, 2), b512, 0, stream>>>(
      wqk, 1024, 0, 1024L * 1024, xbf, 1024, 0, 0,
      (void*)qhat, 4096, 0, 4L * 1024 * 4096, 1024L * 4096, 12, 1024, 1.0f);
  // stage 1b: v = xbf @ Wv^T  (M=16384, N=1024, K=1024)
  gemm_nt256<false><<<dim3(64, 4, 1), b512, 0, stream>>>(
      xbf, 1024, 0, 0, wv, 1024, 0, 0,
      (void*)vbuf, 1024, 0, 0, NOF, NSH, 1024, 1.0f);
  // stage 2: att partials; z=b*4+p: A/B offset = b*(1024*4096) + p*1024 (lda=4096)
  gemm_nt256<true><<<dim3(4, 4, 16), b512, 0, stream>>>(
      qhat, 4096, 1L << 22, 1024, khat, 4096, 1L << 22, 1024,
      (void*)attp, 1024, 4L << 20, 1L << 20, NOF, NSH, 1024, 1.0f / 32.0f);
  // stage 3: reduce partials + softmax -> P bf16
  softmax_reduce4<<<dim3(4096), b256, 0, stream>>>(attp, P);
  // stage 4: out[b] = v[b] @ P[b]^T  (M=4096, N=1024, K=1024, z=b)
  gemm_nt256<false><<<dim3(16, 4, 4), b512, 0, stream>>>(
      vbuf, 1024, 0, 1L << 22, P, 1024, 0, 1L << 20,
      (void*)outb, 1024, 0, 1L << 22, NOF, NSH, 1024, 1.0f);
  // stage 5: final = out @ Wo^T  (M=16384, N=1024, K=1024) -> d_out fp32
  gemm_nt256<true><<<dim3(64, 4, 1), b512, 0, stream>>>(
      outb, 1024, 0, 0, wo, 1024, 0, 0,
      d_out, 1024, 0, 0, NOF, NSH, 1024, 1.0f);
}